// Round 8
// baseline (81.102 us; speedup 1.0000x reference)
//
#include <hip/hip_runtime.h>
#include <hip/hip_bf16.h>

// Geometry
#define NW 64          // N*W = 4*16
#define P 128          // rows per (n,w)
#define D 96           // channels
#define PD (P*D)
#define GCH 101
#define SIM 100
#define LCH 80
#define RSQRT96 0.10206207261596577f   // 1/sqrt(96)

// ws layout (float offsets)
#define WS_SCALE 0                     // 128 floats
#define WS_Q     128                   // 64*128*96   [r][c]  (pre-scaled by 1/sqrt96)
#define WS_KT    (128 + 786432)        // 64*96*128   [c][r] transposed
#define WS_VO    (128 + 2*786432)      // 64*128*96   [r][c]

typedef unsigned long long ull;

// key = (ordered_u32(value) << 32) | (127 - idx): strict total order,
// ties -> lower idx wins. Matches top_k + sort-index semantics exactly.
__device__ __forceinline__ ull make_key(float a, int idx) {
  unsigned u = __float_as_uint(a);
  unsigned msk = (u & 0x80000000u) ? 0xFFFFFFFFu : 0x80000000u;
  return (((ull)(u ^ msk)) << 32) | (unsigned)(127 - idx);
}

// Proj: LDS-tiled GEMM, register tile 2 rows x 12 cols per thread.
// grid 768 = 8 xcd * 96; XCD-swizzled so all blocks of an nw share one XCD's L2.
//   pj=0 -> Q = (scale0*(vq@Wq^T)+b_q)*rsqrt96;  pj=1 -> K^T [c][r];  pj=2 -> VO.
__global__ __launch_bounds__(128, 2) void proj_kernel(const float* __restrict__ v,
    const float* __restrict__ wq, const float* __restrict__ bq,
    const float* __restrict__ wk, const float* __restrict__ wo,
    const float* __restrict__ mb, const float* __restrict__ w_up,
    const float* __restrict__ b_up, float* __restrict__ ws) {
  int bid = blockIdx.x;
  int xcd = bid & 7;
  int m = bid >> 3;          // 0..95
  int g = m / 12;            // 0..7
  int rem = m - g * 12;      // 0..11
  int nw = (g << 3) | xcd;   // all 12 blocks of nw land on XCD (nw&7)
  int pj = rem >> 2, rh = rem & 3;
  const float* W = (pj == 0) ? wq : (pj == 1) ? wk : wo;
  __shared__ float sWt[96 * 100];   // [d][c] stride 100: 16B-aligned rows
  __shared__ float sV[32 * 97];     // [r][d] stride 97: conflict-free b32
  int t = threadIdx.x;
  int ty = t >> 3;   // 0..15 -> row pair
  int tx = t & 7;    // 0..7  -> col group of 12

  for (int k = 0; k < 72; ++k) {
    int idx = t + 128 * k;
    int c = idx / 96, d = idx - c * 96;
    sWt[d * 100 + c] = W[idx];
  }
  const float* Vg = v + (size_t)nw * PD + rh * (32 * D);
#pragma unroll
  for (int i = 0; i < 6; ++i) {
    int idx = (t + 128 * i) * 4;
    float4 x = *(const float4*)(Vg + idx);
    int r = idx / 96, d = idx - r * 96;
    float* p = &sV[r * 97 + d];
    p[0] = x.x; p[1] = x.y; p[2] = x.z; p[3] = x.w;
  }
  float scale0 = 0.f;
  if (pj == 0) {
    float a = b_up[0];
    for (int j = 0; j < LCH; ++j) a += w_up[j] * mb[j];
    scale0 = RSQRT96 / (1.f + __expf(-a));   // fold 1/sqrt(96) into Q
  }
  __syncthreads();

  float acc[2][12];
#pragma unroll
  for (int a = 0; a < 2; ++a)
#pragma unroll
    for (int j = 0; j < 12; ++j) acc[a][j] = 0.f;

  for (int d = 0; d < 96; ++d) {
    float va0 = sV[(ty * 2 + 0) * 97 + d];
    float va1 = sV[(ty * 2 + 1) * 97 + d];
    const float4* wp = (const float4*)&sWt[d * 100 + tx * 12];
    float4 w0 = wp[0], w1 = wp[1], w2 = wp[2];
    float wb[12] = {w0.x,w0.y,w0.z,w0.w, w1.x,w1.y,w1.z,w1.w, w2.x,w2.y,w2.z,w2.w};
#pragma unroll
    for (int j = 0; j < 12; ++j) {
      acc[0][j] += va0 * wb[j];
      acc[1][j] += va1 * wb[j];
    }
  }

  if (pj == 1) {
    float* ktp = ws + WS_KT + nw * PD;
#pragma unroll
    for (int a = 0; a < 2; ++a) {
      int r = rh * 32 + ty * 2 + a;
#pragma unroll
      for (int j = 0; j < 12; ++j)
        ktp[(tx * 12 + j) * P + r] = acc[a][j];
    }
  } else {
    float* outp = ws + ((pj == 0) ? WS_Q : WS_VO) + nw * PD + (rh * 32) * D;
    float4 bq4[3];
    if (pj == 0) {
      const float4* bp = (const float4*)(bq + tx * 12);
      bq4[0] = bp[0]; bq4[1] = bp[1]; bq4[2] = bp[2];
#pragma unroll
      for (int q = 0; q < 3; ++q) {
        bq4[q].x *= RSQRT96; bq4[q].y *= RSQRT96;
        bq4[q].z *= RSQRT96; bq4[q].w *= RSQRT96;
      }
    }
#pragma unroll
    for (int a = 0; a < 2; ++a) {
      float* orow = outp + (ty * 2 + a) * D + tx * 12;
#pragma unroll
      for (int q = 0; q < 3; ++q) {
        float4 o;
        o.x = acc[a][4*q+0]; o.y = acc[a][4*q+1];
        o.z = acc[a][4*q+2]; o.w = acc[a][4*q+3];
        if (pj == 0) {
          o.x = scale0 * o.x + bq4[q].x; o.y = scale0 * o.y + bq4[q].y;
          o.z = scale0 * o.z + bq4[q].z; o.w = scale0 * o.w + bq4[q].w;
        }
        *(float4*)(orow + 4 * q) = o;
      }
    }
  }

  if (bid == 0 && t < GCH) {
    float a = b_up[t];
    for (int j = 0; j < LCH; ++j) a += w_up[t * LCH + j] * mb[j];
    ws[WS_SCALE + t] = 1.f / (1.f + __expf(-a));
  }
}

// Attn: 256-thr blocks = 4 INDEPENDENT waves (no barriers), each wave owns a
// 2-row tile; lane owns cols {2l,2l+1} (float2 loads). 1024 blocks, XCD-
// swizzled (nw&7 == bid&7) so Kt/VO/Q stay in one XCD's L2.
// Multi-wave blocks bypass the 1-wave-workgroup residency cap seen in R5-R7
// (Occupancy stuck ~20%). PV: T staged in wave-private LDS, broadcast
// ds_read_b128 (uniform addr) instead of 256 readlane SGPR chains.
__global__ __launch_bounds__(256) void attn_kernel(const float* __restrict__ attn,
    const float* __restrict__ bo, const float* __restrict__ ws,
    float* __restrict__ out) {
  int bid = blockIdx.x;             // 0..1023
  int xcd = bid & 7;
  int k = (bid >> 3) & 15;          // tile within nw
  int g = bid >> 7;                 // 0..7
  int nw = (g << 3) | xcd;
  int wv = threadIdx.x >> 6;        // 0..3 (independent waves)
  int lane = threadIdx.x & 63;
  int p0 = (k * 4 + wv) * 2;
  __shared__ float sT[4][2][128];   // per-wave T staging (4KB)

  const float* Kt  = ws + WS_KT + nw * PD;
  const float* VO  = ws + WS_VO + nw * PD;
  const float* Qb  = ws + WS_Q  + nw * PD + p0 * D;
  const float* Ab  = attn + (size_t)(nw * P + p0) * P;
  const float* scl = ws + WS_SCALE;

  // per-lane keys: cols 2l (even), 2l+1 (odd) of rows p0, p0+1
  ull ke[2], ko[2];
#pragma unroll
  for (int r = 0; r < 2; ++r) {
    float2 a2 = ((const float2*)(Ab + r * P))[lane];
    ke[r] = make_key(a2.x, 2 * lane);
    ko[r] = make_key(a2.y, 2 * lane + 1);
  }

  // exact stable top-100 rank; uniform side chunked to SGPRs
  int ce[2] = {0, 0}, co_[2] = {0, 0};
  for (int jb = 0; jb < P; jb += 8) {
    float aj[2][8];
#pragma unroll
    for (int r = 0; r < 2; ++r)
#pragma unroll
      for (int i = 0; i < 8; ++i) aj[r][i] = Ab[r * P + jb + i];
#pragma unroll
    for (int i = 0; i < 8; ++i) {
      int j = jb + i;
#pragma unroll
      for (int r = 0; r < 2; ++r) {
        ull kj = make_key(aj[r][i], j);   // uniform: SALU build
        ce[r]  += (kj > ke[r]) ? 1 : 0;   // v_cmp_gt_u64 + addc
        co_[r] += (kj > ko[r]) ? 1 : 0;
      }
    }
  }

  // S[r][2l], S[r][2l+1]: q uniform (chunked), Kt float2 coalesced
  float se[2] = {0, 0}, so[2] = {0, 0};
  for (int cb = 0; cb < D; cb += 8) {
    float q[2][8];
#pragma unroll
    for (int r = 0; r < 2; ++r)
#pragma unroll
      for (int i = 0; i < 8; ++i) q[r][i] = Qb[r * D + cb + i];
#pragma unroll
    for (int i = 0; i < 8; ++i) {
      float2 kv = ((const float2*)(Kt + (cb + i) * P))[lane];
#pragma unroll
      for (int r = 0; r < 2; ++r) {
        se[r] += q[r][i] * kv.x;
        so[r] += q[r][i] * kv.y;
      }
    }
  }

  // keep, position among kept (sorted idx order), scale, softmax, T -> LDS
  ull lm = (1ull << lane) - 1ull;
#pragma unroll
  for (int r = 0; r < 2; ++r) {
    bool kpe = ce[r] < SIM, kpo = co_[r] < SIM;
    ull be = __ballot(kpe), bo_ = __ballot(kpo);
    int pe = __popcll(be & lm) + __popcll(bo_ & lm);   // kept cols < 2l
    int po = pe + (kpe ? 1 : 0);                        // + col 2l itself
    float sve = kpe ? scl[1 + pe] : 0.f;
    float svo = kpo ? scl[1 + po] : 0.f;
    float xe = kpe ? sve * se[r] : -1e30f;   // rsqrt96 pre-folded into Q
    float xo = kpo ? svo * so[r] : -1e30f;
    float mx = fmaxf(xe, xo);
#pragma unroll
    for (int off = 1; off < 64; off <<= 1) mx = fmaxf(mx, __shfl_xor(mx, off));
    float ee = kpe ? __expf(xe - mx) : 0.f;
    float eo = kpo ? __expf(xo - mx) : 0.f;
    float s = ee + eo;
#pragma unroll
    for (int off = 1; off < 64; off <<= 1) s += __shfl_xor(s, off);
    float inv = 1.f / s;
    float2 tw; tw.x = ee * inv * sve; tw.y = eo * inv * svo;
    ((float2*)sT[wv][r])[lane] = tw;   // wave-private; in-order, no barrier
  }

  // out[r][c] = sum_j T[r][j]*VO[j][c] + b_o[c]; lane owns c={2lc,2lc+1}
  int lc = (lane < 48) ? lane : 47;   // lanes 48-63 compute junk, don't store
  float2 o0 = {0.f, 0.f}, o1 = {0.f, 0.f};
#pragma unroll 2
  for (int jb = 0; jb < P; jb += 4) {
    float4 t0 = *(const float4*)&sT[wv][0][jb];  // uniform addr -> broadcast
    float4 t1 = *(const float4*)&sT[wv][1][jb];
    float tb0[4] = {t0.x, t0.y, t0.z, t0.w};
    float tb1[4] = {t1.x, t1.y, t1.z, t1.w};
#pragma unroll
    for (int jj = 0; jj < 4; ++jj) {
      float2 vo = ((const float2*)(VO + (jb + jj) * D))[lc];
      o0.x += tb0[jj] * vo.x; o0.y += tb0[jj] * vo.y;
      o1.x += tb1[jj] * vo.x; o1.y += tb1[jj] * vo.y;
    }
  }
  if (lane < 48) {
    float2 bb = ((const float2*)bo)[lane];
    float* op = out + (size_t)(nw * P + p0) * D;
    float2 r0; r0.x = o0.x + bb.x; r0.y = o0.y + bb.y;
    float2 r1; r1.x = o1.x + bb.x; r1.y = o1.y + bb.y;
    ((float2*)(op + 0 * D))[lane] = r0;
    ((float2*)(op + 1 * D))[lane] = r1;
  }
}

extern "C" void kernel_launch(void* const* d_in, const int* in_sizes, int n_in,
                              void* d_out, int out_size, void* d_ws, size_t ws_size,
                              hipStream_t stream) {
  const float* attn = (const float*)d_in[0];
  const float* v    = (const float*)d_in[1];
  const float* mb   = (const float*)d_in[2];
  // d_in[3]=w_sub, d_in[4]=b_sub: dead (softmax over singleton axis == 1)
  const float* w_up = (const float*)d_in[5];
  const float* b_up = (const float*)d_in[6];
  const float* w_q  = (const float*)d_in[7];
  const float* b_q  = (const float*)d_in[8];
  const float* w_k  = (const float*)d_in[9];
  // d_in[10]=b_k: constant shift per row -> drops out of softmax, unused
  const float* w_o  = (const float*)d_in[11];
  const float* b_o  = (const float*)d_in[12];
  float* out = (float*)d_out;
  float* ws = (float*)d_ws;

  hipLaunchKernelGGL(proj_kernel, dim3(768), dim3(128), 0, stream,
                     v, w_q, b_q, w_k, w_o, mb, w_up, b_up, ws);
  hipLaunchKernelGGL(attn_kernel, dim3(1024), dim3(256), 0, stream,
                     attn, b_o, ws, out);
}

// Round 9
// 65.420 us; speedup vs baseline: 1.2397x; 1.2397x over previous
//
#include <hip/hip_runtime.h>
#include <hip/hip_bf16.h>

// Geometry
#define NW 64          // N*W = 4*16
#define P 128          // rows per (n,w)
#define D 96           // channels
#define PD (P*D)
#define GCH 101
#define SIM 100
#define LCH 80
#define RSQRT96 0.10206207261596577f   // 1/sqrt(96)

// ws layout (float offsets)
#define WS_SCALE 0                     // 128 floats
#define WS_Q     128                   // 64*128*96   [r][c]  (pre-scaled by 1/sqrt96)
#define WS_KT    (128 + 786432)        // 64*96*128   [c][r] transposed
#define WS_VO    (128 + 2*786432)      // 64*128*96   [r][c]

typedef unsigned long long ull;

// key = (ordered_u32(value) << 32) | (127 - idx): strict total order,
// ties -> lower idx wins. Matches top_k + sort-index semantics exactly.
__device__ __forceinline__ ull make_key(float a, int idx) {
  unsigned u = __float_as_uint(a);
  unsigned msk = (u & 0x80000000u) ? 0xFFFFFFFFu : 0x80000000u;
  return (((ull)(u ^ msk)) << 32) | (unsigned)(127 - idx);
}

// Proj: LDS-tiled GEMM, register tile 2 rows x 12 cols per thread.
// grid 768 = 8 xcd * 96; XCD-swizzled so all blocks of an nw share one XCD's L2.
//   pj=0 -> Q = (scale0*(vq@Wq^T)+b_q)*rsqrt96;  pj=1 -> K^T [c][r];  pj=2 -> VO.
__global__ __launch_bounds__(128, 2) void proj_kernel(const float* __restrict__ v,
    const float* __restrict__ wq, const float* __restrict__ bq,
    const float* __restrict__ wk, const float* __restrict__ wo,
    const float* __restrict__ mb, const float* __restrict__ w_up,
    const float* __restrict__ b_up, float* __restrict__ ws) {
  int bid = blockIdx.x;
  int xcd = bid & 7;
  int m = bid >> 3;          // 0..95
  int g = m / 12;            // 0..7
  int rem = m - g * 12;      // 0..11
  int nw = (g << 3) | xcd;   // all 12 blocks of nw land on XCD (nw&7)
  int pj = rem >> 2, rh = rem & 3;
  const float* W = (pj == 0) ? wq : (pj == 1) ? wk : wo;
  __shared__ float sWt[96 * 100];   // [d][c] stride 100: 16B-aligned rows
  __shared__ float sV[32 * 97];     // [r][d] stride 97: conflict-free b32
  int t = threadIdx.x;
  int ty = t >> 3;   // 0..15 -> row pair
  int tx = t & 7;    // 0..7  -> col group of 12

  for (int k = 0; k < 72; ++k) {
    int idx = t + 128 * k;
    int c = idx / 96, d = idx - c * 96;
    sWt[d * 100 + c] = W[idx];
  }
  const float* Vg = v + (size_t)nw * PD + rh * (32 * D);
#pragma unroll
  for (int i = 0; i < 6; ++i) {
    int idx = (t + 128 * i) * 4;
    float4 x = *(const float4*)(Vg + idx);
    int r = idx / 96, d = idx - r * 96;
    float* p = &sV[r * 97 + d];
    p[0] = x.x; p[1] = x.y; p[2] = x.z; p[3] = x.w;
  }
  float scale0 = 0.f;
  if (pj == 0) {
    float a = b_up[0];
    for (int j = 0; j < LCH; ++j) a += w_up[j] * mb[j];
    scale0 = RSQRT96 / (1.f + __expf(-a));   // fold 1/sqrt(96) into Q
  }
  __syncthreads();

  float acc[2][12];
#pragma unroll
  for (int a = 0; a < 2; ++a)
#pragma unroll
    for (int j = 0; j < 12; ++j) acc[a][j] = 0.f;

  for (int d = 0; d < 96; ++d) {
    float va0 = sV[(ty * 2 + 0) * 97 + d];
    float va1 = sV[(ty * 2 + 1) * 97 + d];
    const float4* wp = (const float4*)&sWt[d * 100 + tx * 12];
    float4 w0 = wp[0], w1 = wp[1], w2 = wp[2];
    float wb[12] = {w0.x,w0.y,w0.z,w0.w, w1.x,w1.y,w1.z,w1.w, w2.x,w2.y,w2.z,w2.w};
#pragma unroll
    for (int j = 0; j < 12; ++j) {
      acc[0][j] += va0 * wb[j];
      acc[1][j] += va1 * wb[j];
    }
  }

  if (pj == 1) {
    float* ktp = ws + WS_KT + nw * PD;
#pragma unroll
    for (int a = 0; a < 2; ++a) {
      int r = rh * 32 + ty * 2 + a;
#pragma unroll
      for (int j = 0; j < 12; ++j)
        ktp[(tx * 12 + j) * P + r] = acc[a][j];
    }
  } else {
    float* outp = ws + ((pj == 0) ? WS_Q : WS_VO) + nw * PD + (rh * 32) * D;
    float4 bq4[3];
    if (pj == 0) {
      const float4* bp = (const float4*)(bq + tx * 12);
      bq4[0] = bp[0]; bq4[1] = bp[1]; bq4[2] = bp[2];
#pragma unroll
      for (int q = 0; q < 3; ++q) {
        bq4[q].x *= RSQRT96; bq4[q].y *= RSQRT96;
        bq4[q].z *= RSQRT96; bq4[q].w *= RSQRT96;
      }
    }
#pragma unroll
    for (int a = 0; a < 2; ++a) {
      float* orow = outp + (ty * 2 + a) * D + tx * 12;
#pragma unroll
      for (int q = 0; q < 3; ++q) {
        float4 o;
        o.x = acc[a][4*q+0]; o.y = acc[a][4*q+1];
        o.z = acc[a][4*q+2]; o.w = acc[a][4*q+3];
        if (pj == 0) {
          o.x = scale0 * o.x + bq4[q].x; o.y = scale0 * o.y + bq4[q].y;
          o.z = scale0 * o.z + bq4[q].z; o.w = scale0 * o.w + bq4[q].w;
        }
        *(float4*)(orow + 4 * q) = o;
      }
    }
  }

  if (bid == 0 && t < GCH) {
    float a = b_up[t];
    for (int j = 0; j < LCH; ++j) a += w_up[t * LCH + j] * mb[j];
    ws[WS_SCALE + t] = 1.f / (1.f + __expf(-a));
  }
}

// Attn: 256-thr blocks = 4 INDEPENDENT waves (no barriers), each wave a 2-row
// tile; lane owns cols {2l,2l+1}. 1024 blocks, XCD-swizzled.
// CRITICAL (R8 lesson): wave id must go through readfirstlane so address math
// stays provably wave-uniform -> s_load/SALU path (SGPR~112, VGPR~108). A raw
// threadIdx-derived wv turned all uniform loads into vector loads (SGPR 32,
// VGPR 200, occupancy 11%). launch_bounds (256,2): VGPR cap 128 = 256/min_waves.
__global__ __launch_bounds__(256, 2) void attn_kernel(const float* __restrict__ attn,
    const float* __restrict__ bo, const float* __restrict__ ws,
    float* __restrict__ out) {
  int bid = blockIdx.x;             // 0..1023
  int xcd = bid & 7;
  int k = (bid >> 3) & 15;          // tile within nw
  int g = bid >> 7;                 // 0..7
  int nw = (g << 3) | xcd;
  int wvu = __builtin_amdgcn_readfirstlane(threadIdx.x >> 6);  // SGPR wave id
  int lane = threadIdx.x & 63;
  int p0 = (k * 4 + wvu) * 2;
  __shared__ float sT[4][2][128];   // per-wave T staging (4KB)

  const float* Kt  = ws + WS_KT + nw * PD;
  const float* VO  = ws + WS_VO + nw * PD;
  const float* Qb  = ws + WS_Q  + nw * PD + p0 * D;
  const float* Ab  = attn + (size_t)(nw * P + p0) * P;
  const float* scl = ws + WS_SCALE;

  // per-lane keys: cols 2l (even), 2l+1 (odd) of rows p0, p0+1
  ull ke[2], ko[2];
#pragma unroll
  for (int r = 0; r < 2; ++r) {
    float2 a2 = ((const float2*)(Ab + r * P))[lane];
    ke[r] = make_key(a2.x, 2 * lane);
    ko[r] = make_key(a2.y, 2 * lane + 1);
  }

  // exact stable top-100 rank; uniform side chunked to SGPRs
  int ce[2] = {0, 0}, co_[2] = {0, 0};
  for (int jb = 0; jb < P; jb += 8) {
    float aj[2][8];
#pragma unroll
    for (int r = 0; r < 2; ++r)
#pragma unroll
      for (int i = 0; i < 8; ++i) aj[r][i] = Ab[r * P + jb + i];
#pragma unroll
    for (int i = 0; i < 8; ++i) {
      int j = jb + i;
#pragma unroll
      for (int r = 0; r < 2; ++r) {
        ull kj = make_key(aj[r][i], j);   // uniform: SALU build
        ce[r]  += (kj > ke[r]) ? 1 : 0;   // v_cmp_gt_u64 + addc
        co_[r] += (kj > ko[r]) ? 1 : 0;
      }
    }
  }

  // S[r][2l], S[r][2l+1]: q uniform (chunked), Kt float2 coalesced
  float se[2] = {0, 0}, so[2] = {0, 0};
  for (int cb = 0; cb < D; cb += 8) {
    float q[2][8];
#pragma unroll
    for (int r = 0; r < 2; ++r)
#pragma unroll
      for (int i = 0; i < 8; ++i) q[r][i] = Qb[r * D + cb + i];
#pragma unroll
    for (int i = 0; i < 8; ++i) {
      float2 kv = ((const float2*)(Kt + (cb + i) * P))[lane];
#pragma unroll
      for (int r = 0; r < 2; ++r) {
        se[r] += q[r][i] * kv.x;
        so[r] += q[r][i] * kv.y;
      }
    }
  }

  // keep, position among kept (sorted idx order), scale, softmax, T -> LDS
  ull lm = (1ull << lane) - 1ull;
#pragma unroll
  for (int r = 0; r < 2; ++r) {
    bool kpe = ce[r] < SIM, kpo = co_[r] < SIM;
    ull be = __ballot(kpe), bo_ = __ballot(kpo);
    int pe = __popcll(be & lm) + __popcll(bo_ & lm);   // kept cols < 2l
    int po = pe + (kpe ? 1 : 0);                        // + col 2l itself
    float sve = kpe ? scl[1 + pe] : 0.f;
    float svo = kpo ? scl[1 + po] : 0.f;
    float xe = kpe ? sve * se[r] : -1e30f;   // rsqrt96 pre-folded into Q
    float xo = kpo ? svo * so[r] : -1e30f;
    float mx = fmaxf(xe, xo);
#pragma unroll
    for (int off = 1; off < 64; off <<= 1) mx = fmaxf(mx, __shfl_xor(mx, off));
    float ee = kpe ? __expf(xe - mx) : 0.f;
    float eo = kpo ? __expf(xo - mx) : 0.f;
    float s = ee + eo;
#pragma unroll
    for (int off = 1; off < 64; off <<= 1) s += __shfl_xor(s, off);
    float inv = 1.f / s;
    float2 tw; tw.x = ee * inv * sve; tw.y = eo * inv * svo;
    ((float2*)sT[wvu][r])[lane] = tw;   // wave-private; in-order, no barrier
  }

  // out[r][c] = sum_j T[r][j]*VO[j][c] + b_o[c]; lane owns c={2lc,2lc+1}
  int lc = (lane < 48) ? lane : 47;   // lanes 48-63 compute junk, don't store
  float2 o0 = {0.f, 0.f}, o1 = {0.f, 0.f};
#pragma unroll 2
  for (int jb = 0; jb < P; jb += 4) {
    float4 t0 = *(const float4*)&sT[wvu][0][jb];  // uniform addr -> broadcast
    float4 t1 = *(const float4*)&sT[wvu][1][jb];
    float tb0[4] = {t0.x, t0.y, t0.z, t0.w};
    float tb1[4] = {t1.x, t1.y, t1.z, t1.w};
#pragma unroll
    for (int jj = 0; jj < 4; ++jj) {
      float2 vo = ((const float2*)(VO + (jb + jj) * D))[lc];
      o0.x += tb0[jj] * vo.x; o0.y += tb0[jj] * vo.y;
      o1.x += tb1[jj] * vo.x; o1.y += tb1[jj] * vo.y;
    }
  }
  if (lane < 48) {
    float2 bb = ((const float2*)bo)[lane];
    float* op = out + (size_t)(nw * P + p0) * D;
    float2 r0; r0.x = o0.x + bb.x; r0.y = o0.y + bb.y;
    float2 r1; r1.x = o1.x + bb.x; r1.y = o1.y + bb.y;
    ((float2*)(op + 0 * D))[lane] = r0;
    ((float2*)(op + 1 * D))[lane] = r1;
  }
}

extern "C" void kernel_launch(void* const* d_in, const int* in_sizes, int n_in,
                              void* d_out, int out_size, void* d_ws, size_t ws_size,
                              hipStream_t stream) {
  const float* attn = (const float*)d_in[0];
  const float* v    = (const float*)d_in[1];
  const float* mb   = (const float*)d_in[2];
  // d_in[3]=w_sub, d_in[4]=b_sub: dead (softmax over singleton axis == 1)
  const float* w_up = (const float*)d_in[5];
  const float* b_up = (const float*)d_in[6];
  const float* w_q  = (const float*)d_in[7];
  const float* b_q  = (const float*)d_in[8];
  const float* w_k  = (const float*)d_in[9];
  // d_in[10]=b_k: constant shift per row -> drops out of softmax, unused
  const float* w_o  = (const float*)d_in[11];
  const float* b_o  = (const float*)d_in[12];
  float* out = (float*)d_out;
  float* ws = (float*)d_ws;

  hipLaunchKernelGGL(proj_kernel, dim3(768), dim3(128), 0, stream,
                     v, w_q, b_q, w_k, w_o, mb, w_up, b_up, ws);
  hipLaunchKernelGGL(attn_kernel, dim3(1024), dim3(256), 0, stream,
                     attn, b_o, ws, out);
}

// Round 10
// 58.457 us; speedup vs baseline: 1.3874x; 1.1191x over previous
//
#include <hip/hip_runtime.h>
#include <hip/hip_bf16.h>

// Geometry
#define NW 64          // N*W = 4*16
#define P 128          // rows per (n,w)
#define D 96           // channels
#define PD (P*D)
#define GCH 101
#define SIM 100
#define LCH 80
#define RSQRT96 0.10206207261596577f   // 1/sqrt(96)

// ws layout (float offsets)
#define WS_SCALE 0                     // 128 floats
#define WS_Q     128                   // 64*128*96   [r][c]  (pre-scaled by 1/sqrt96)
#define WS_KT    (128 + 786432)        // 64*96*128   [c][r] transposed
#define WS_VO    (128 + 2*786432)      // 64*128*96   [r][c]

typedef unsigned long long ull;

__device__ __forceinline__ unsigned ord_u32(float a) {
  unsigned u = __float_as_uint(a);
  unsigned msk = (u & 0x80000000u) ? 0xFFFFFFFFu : 0x80000000u;
  return u ^ msk;   // monotone: float order == uint order
}

// Proj: LDS-tiled GEMM, register tile 2 rows x 12 cols per thread.
// grid 768 = 8 xcd * 96; XCD-swizzled so all blocks of an nw share one XCD's L2.
//   pj=0 -> Q = (scale0*(vq@Wq^T)+b_q)*rsqrt96;  pj=1 -> K^T [c][r];  pj=2 -> VO.
__global__ __launch_bounds__(128, 2) void proj_kernel(const float* __restrict__ v,
    const float* __restrict__ wq, const float* __restrict__ bq,
    const float* __restrict__ wk, const float* __restrict__ wo,
    const float* __restrict__ mb, const float* __restrict__ w_up,
    const float* __restrict__ b_up, float* __restrict__ ws) {
  int bid = blockIdx.x;
  int xcd = bid & 7;
  int m = bid >> 3;          // 0..95
  int g = m / 12;            // 0..7
  int rem = m - g * 12;      // 0..11
  int nw = (g << 3) | xcd;   // all 12 blocks of nw land on XCD (nw&7)
  int pj = rem >> 2, rh = rem & 3;
  const float* W = (pj == 0) ? wq : (pj == 1) ? wk : wo;
  __shared__ float sWt[96 * 100];   // [d][c] stride 100: 16B-aligned rows
  __shared__ float sV[32 * 97];     // [r][d] stride 97: conflict-free b32
  int t = threadIdx.x;
  int ty = t >> 3;   // 0..15 -> row pair
  int tx = t & 7;    // 0..7  -> col group of 12

  for (int k = 0; k < 72; ++k) {
    int idx = t + 128 * k;
    int c = idx / 96, d = idx - c * 96;
    sWt[d * 100 + c] = W[idx];
  }
  const float* Vg = v + (size_t)nw * PD + rh * (32 * D);
#pragma unroll
  for (int i = 0; i < 6; ++i) {
    int idx = (t + 128 * i) * 4;
    float4 x = *(const float4*)(Vg + idx);
    int r = idx / 96, d = idx - r * 96;
    float* p = &sV[r * 97 + d];
    p[0] = x.x; p[1] = x.y; p[2] = x.z; p[3] = x.w;
  }
  float scale0 = 0.f;
  if (pj == 0) {
    float a = b_up[0];
    for (int j = 0; j < LCH; ++j) a += w_up[j] * mb[j];
    scale0 = RSQRT96 / (1.f + __expf(-a));   // fold 1/sqrt(96) into Q
  }
  __syncthreads();

  float acc[2][12];
#pragma unroll
  for (int a = 0; a < 2; ++a)
#pragma unroll
    for (int j = 0; j < 12; ++j) acc[a][j] = 0.f;

  for (int d = 0; d < 96; ++d) {
    float va0 = sV[(ty * 2 + 0) * 97 + d];
    float va1 = sV[(ty * 2 + 1) * 97 + d];
    const float4* wp = (const float4*)&sWt[d * 100 + tx * 12];
    float4 w0 = wp[0], w1 = wp[1], w2 = wp[2];
    float wb[12] = {w0.x,w0.y,w0.z,w0.w, w1.x,w1.y,w1.z,w1.w, w2.x,w2.y,w2.z,w2.w};
#pragma unroll
    for (int j = 0; j < 12; ++j) {
      acc[0][j] += va0 * wb[j];
      acc[1][j] += va1 * wb[j];
    }
  }

  if (pj == 1) {
    float* ktp = ws + WS_KT + nw * PD;
#pragma unroll
    for (int a = 0; a < 2; ++a) {
      int r = rh * 32 + ty * 2 + a;
#pragma unroll
      for (int j = 0; j < 12; ++j)
        ktp[(tx * 12 + j) * P + r] = acc[a][j];
    }
  } else {
    float* outp = ws + ((pj == 0) ? WS_Q : WS_VO) + nw * PD + (rh * 32) * D;
    float4 bq4[3];
    if (pj == 0) {
      const float4* bp = (const float4*)(bq + tx * 12);
      bq4[0] = bp[0]; bq4[1] = bp[1]; bq4[2] = bp[2];
#pragma unroll
      for (int q = 0; q < 3; ++q) {
        bq4[q].x *= RSQRT96; bq4[q].y *= RSQRT96;
        bq4[q].z *= RSQRT96; bq4[q].w *= RSQRT96;
      }
    }
#pragma unroll
    for (int a = 0; a < 2; ++a) {
      float* orow = outp + (ty * 2 + a) * D + tx * 12;
#pragma unroll
      for (int q = 0; q < 3; ++q) {
        float4 o;
        o.x = acc[a][4*q+0]; o.y = acc[a][4*q+1];
        o.z = acc[a][4*q+2]; o.w = acc[a][4*q+3];
        if (pj == 0) {
          o.x = scale0 * o.x + bq4[q].x; o.y = scale0 * o.y + bq4[q].y;
          o.z = scale0 * o.z + bq4[q].z; o.w = scale0 * o.w + bq4[q].w;
        }
        *(float4*)(orow + 4 * q) = o;
      }
    }
  }

  if (bid == 0 && t < GCH) {
    float a = b_up[t];
    for (int j = 0; j < LCH; ++j) a += w_up[t * LCH + j] * mb[j];
    ws[WS_SCALE + t] = 1.f / (1.f + __expf(-a));
  }
}

// Attn: 256-thr blocks = 4 independent waves, each wave a 2-row tile; lane owns
// cols {2l,2l+1}. 1024 blocks, XCD-swizzled. R10: serial-latency fix —
//  (1) rank phase is 100% register ops: uniform key hi-word via readlane
//      (keys already live in lanes), low word is a per-j constant. Zero loads.
//  (2) S-loop: 6 chunks of 16 (16 VMEM in flight + 2 s_load_dwordx8, 1 wait).
//  (3) PV: 8 chunks of 16 (16 VO loads in flight per chunk).
// wvu via readfirstlane (R8 lesson: keeps uniform loads on the SALU path).
__global__ __launch_bounds__(256, 2) void attn_kernel(const float* __restrict__ attn,
    const float* __restrict__ bo, const float* __restrict__ ws,
    float* __restrict__ out) {
  int bid = blockIdx.x;             // 0..1023
  int xcd = bid & 7;
  int k = (bid >> 3) & 15;          // tile within nw
  int g = bid >> 7;                 // 0..7
  int nw = (g << 3) | xcd;
  int wvu = __builtin_amdgcn_readfirstlane(threadIdx.x >> 6);  // SGPR wave id
  int lane = threadIdx.x & 63;
  int p0 = (k * 4 + wvu) * 2;
  __shared__ float sT[4][2][128];   // per-wave T staging (4KB)

  const float* Kt  = ws + WS_KT + nw * PD;
  const float* VO  = ws + WS_VO + nw * PD;
  const float* Qb  = ws + WS_Q  + nw * PD + p0 * D;
  const float* Ab  = attn + (size_t)(nw * P + p0) * P;
  const float* scl = ws + WS_SCALE;

  // per-lane keys for cols 2l (even), 2l+1 (odd) of rows p0, p0+1
  unsigned he[2], ho[2];   // hi words (ordered u32 of value)
  ull ke[2], ko[2];        // full u64 keys (hi<<32 | (127-idx))
#pragma unroll
  for (int r = 0; r < 2; ++r) {
    float2 a2 = ((const float2*)(Ab + r * P))[lane];
    unsigned ue = ord_u32(a2.x), uo = ord_u32(a2.y);
    he[r] = ue; ho[r] = uo;
    ke[r] = (((ull)ue) << 32) | (unsigned)(127 - 2 * lane);
    ko[r] = (((ull)uo) << 32) | (unsigned)(127 - (2 * lane + 1));
  }

  // rank: register-only. key_j hi via readlane (lane j>>1, even/odd reg),
  // low word = 127-j (uniform constant). cnt = #{j: key_j > mine}.
  int ce[2] = {0, 0}, co_[2] = {0, 0};
#pragma unroll
  for (int j = 0; j < 128; ++j) {
    unsigned lo = (unsigned)(127 - j);
    unsigned h0, h1;
    if ((j & 1) == 0) {
      h0 = (unsigned)__builtin_amdgcn_readlane((int)he[0], j >> 1);
      h1 = (unsigned)__builtin_amdgcn_readlane((int)he[1], j >> 1);
    } else {
      h0 = (unsigned)__builtin_amdgcn_readlane((int)ho[0], j >> 1);
      h1 = (unsigned)__builtin_amdgcn_readlane((int)ho[1], j >> 1);
    }
    ull kj0 = (((ull)h0) << 32) | lo;   // uniform -> SGPR pair
    ull kj1 = (((ull)h1) << 32) | lo;
    ce[0]  += (kj0 > ke[0]) ? 1 : 0;
    co_[0] += (kj0 > ko[0]) ? 1 : 0;
    ce[1]  += (kj1 > ke[1]) ? 1 : 0;
    co_[1] += (kj1 > ko[1]) ? 1 : 0;
  }

  // S: 6 chunks of 16 — deep MLP on Kt loads, q via scalar chunk loads
  float se[2] = {0, 0}, so[2] = {0, 0};
#pragma unroll 1
  for (int cb = 0; cb < D; cb += 16) {
    float2 kv[16];
#pragma unroll
    for (int i = 0; i < 16; ++i)
      kv[i] = ((const float2*)(Kt + (cb + i) * P))[lane];
    float q0[16], q1[16];
#pragma unroll
    for (int i = 0; i < 16; ++i) { q0[i] = Qb[cb + i]; q1[i] = Qb[D + cb + i]; }
#pragma unroll
    for (int i = 0; i < 16; ++i) {
      se[0] += q0[i] * kv[i].x; so[0] += q0[i] * kv[i].y;
      se[1] += q1[i] * kv[i].x; so[1] += q1[i] * kv[i].y;
    }
  }

  // keep, position among kept (sorted idx order), scale, softmax, T -> LDS
  ull lm = (1ull << lane) - 1ull;
#pragma unroll
  for (int r = 0; r < 2; ++r) {
    bool kpe = ce[r] < SIM, kpo = co_[r] < SIM;
    ull be = __ballot(kpe), bo_ = __ballot(kpo);
    int pe = __popcll(be & lm) + __popcll(bo_ & lm);   // kept cols < 2l
    int po = pe + (kpe ? 1 : 0);                        // + col 2l itself
    float sve = kpe ? scl[1 + pe] : 0.f;
    float svo = kpo ? scl[1 + po] : 0.f;
    float xe = kpe ? sve * se[r] : -1e30f;   // rsqrt96 pre-folded into Q
    float xo = kpo ? svo * so[r] : -1e30f;
    float mx = fmaxf(xe, xo);
#pragma unroll
    for (int off = 1; off < 64; off <<= 1) mx = fmaxf(mx, __shfl_xor(mx, off));
    float ee = kpe ? __expf(xe - mx) : 0.f;
    float eo = kpo ? __expf(xo - mx) : 0.f;
    float s = ee + eo;
#pragma unroll
    for (int off = 1; off < 64; off <<= 1) s += __shfl_xor(s, off);
    float inv = 1.f / s;
    float2 tw; tw.x = ee * inv * sve; tw.y = eo * inv * svo;
    ((float2*)sT[wvu][r])[lane] = tw;   // wave-private; in-order, no barrier
  }

  // PV: 8 chunks of 16 — 16 VO loads in flight, T via uniform b128 LDS reads
  int lc = (lane < 48) ? lane : 47;   // lanes 48-63 compute junk, don't store
  float2 o0 = {0.f, 0.f}, o1 = {0.f, 0.f};
#pragma unroll 1
  for (int jb = 0; jb < P; jb += 16) {
    float2 vo[16];
#pragma unroll
    for (int i = 0; i < 16; ++i)
      vo[i] = ((const float2*)(VO + (jb + i) * D))[lc];
    float4 t0v[4], t1v[4];
#pragma unroll
    for (int q = 0; q < 4; ++q) {
      t0v[q] = *(const float4*)&sT[wvu][0][jb + 4 * q];  // uniform -> broadcast
      t1v[q] = *(const float4*)&sT[wvu][1][jb + 4 * q];
    }
#pragma unroll
    for (int q = 0; q < 4; ++q) {
      float ta[4] = {t0v[q].x, t0v[q].y, t0v[q].z, t0v[q].w};
      float tb[4] = {t1v[q].x, t1v[q].y, t1v[q].z, t1v[q].w};
#pragma unroll
      for (int jj = 0; jj < 4; ++jj) {
        float2 vv = vo[4 * q + jj];
        o0.x += ta[jj] * vv.x; o0.y += ta[jj] * vv.y;
        o1.x += tb[jj] * vv.x; o1.y += tb[jj] * vv.y;
      }
    }
  }
  if (lane < 48) {
    float2 bb = ((const float2*)bo)[lane];
    float* op = out + (size_t)(nw * P + p0) * D;
    float2 r0; r0.x = o0.x + bb.x; r0.y = o0.y + bb.y;
    float2 r1; r1.x = o1.x + bb.x; r1.y = o1.y + bb.y;
    ((float2*)(op + 0 * D))[lane] = r0;
    ((float2*)(op + 1 * D))[lane] = r1;
  }
}

extern "C" void kernel_launch(void* const* d_in, const int* in_sizes, int n_in,
                              void* d_out, int out_size, void* d_ws, size_t ws_size,
                              hipStream_t stream) {
  const float* attn = (const float*)d_in[0];
  const float* v    = (const float*)d_in[1];
  const float* mb   = (const float*)d_in[2];
  // d_in[3]=w_sub, d_in[4]=b_sub: dead (softmax over singleton axis == 1)
  const float* w_up = (const float*)d_in[5];
  const float* b_up = (const float*)d_in[6];
  const float* w_q  = (const float*)d_in[7];
  const float* b_q  = (const float*)d_in[8];
  const float* w_k  = (const float*)d_in[9];
  // d_in[10]=b_k: constant shift per row -> drops out of softmax, unused
  const float* w_o  = (const float*)d_in[11];
  const float* b_o  = (const float*)d_in[12];
  float* out = (float*)d_out;
  float* ws = (float*)d_ws;

  hipLaunchKernelGGL(proj_kernel, dim3(768), dim3(128), 0, stream,
                     v, w_q, b_q, w_k, w_o, mb, w_up, b_up, ws);
  hipLaunchKernelGGL(attn_kernel, dim3(1024), dim3(256), 0, stream,
                     attn, b_o, ws, out);
}